// Round 6
// baseline (8816.062 us; speedup 1.0000x reference)
//
#include <hip/hip_runtime.h>

// FPS (farthest point sampling) + gather for B=16, N=65536, S=512, C=64.
// 16 WGs per batch, each owns a 4096-pt chunk in REGISTERS (16 pts/thread).
//
// (Round 6 = round 5 resubmitted verbatim: the round-5 bench died to an
// infra/container failure before running — same signature as round 3, which
// resubmission proved innocent. Audit found no hang risk: decode is
// bijective, sc0 poll has a sticky agent-scope fallback after 4096 spins,
// all waves reach the single barrier, writebacks always carry the newest
// slot value.)
//
// Round-5 change: move the cross-WG sync coherence point from the LLC
// (~900 cyc RT, measured r2->r4 delta) to the per-XCD L2 (~200 cyc):
//  - blockIdx swizzle puts all 16 WGs of a batch on ONE XCD (assuming the
//    measured round-robin blockIdx%8 -> XCD mapping).
//  - Publisher: plain global stores (L1 is write-through -> lands in the
//    XCD-shared L2), THEN agent-scope stores of the same values to the same
//    addresses (LLC path for cross-XCD readers). Same-thread same-address
//    ordering: the agent store resolves/updates the dirty line, so no stale
//    dirty line can ever write back over a newer LLC value.
//  - Poller: `global_load_dword ... sc0` (bypass L1, read L2). If a lane
//    spins too long (wrong mapping or wrong sc0 semantics -> stale clean
//    line in its own L2), it STICKILY degrades to agent-scope loads, which
//    are guaranteed to see the agent stores. Never hangs, never corrupts;
//    worst case = round-4 perf + ~40us one-time.
//
// Slot protocol: THREE self-tagged dwords per wave-slot, each carrying the
// full 16-bit iteration tag:
//    wA  = (it<<16) | idx16
//    wBh = (it<<16) | dist_bits[31:16]
//    wBl = (it<<16) | dist_bits[15:0]
// Accept iff all three tags == it. Any stale value (it-2, it-4, either
// storage tier) has a mismatched tag -> rejected. Dwords are single-copy
// atomic; only 64-bit accesses could tear (the round-0 bug). Double-buffer
// by parity still guarantees gen it's slot is not overwritten before all
// pollers of gen it finished (a WG publishes it+2 only after passing its
// it+1 poll, which is after every WG's end-of-it barrier).
//
// Per-wave publish (4 sub-slots/WG, 64/batch = one per poller lane), wave 0
// polls + reduces, one __syncthreads per iteration (centroid broadcast) --
// unchanged from r4 (1600us rocprof, 3.1us/iter, ~2.6us of it sync latency).

#define NB    16
#define NPTS  65536
#define NS    512
#define WPB   16                 // workgroups per batch
#define CHUNK (NPTS / WPB)       // 4096 points per WG
#define NTHR  256
#define PPT   (CHUNK / NTHR)     // 16 points per thread
#define NWAVE (NTHR / 64)        // 4 waves per WG
#define SPW   (NS / WPB)         // 32 samples gathered per WG
#define NSLOT (WPB * NWAVE)      // 64 sub-slots per batch (one per wave)
#define ARRD  (2 * NB * NSLOT)   // dwords per slot array (parity-doubled)

__device__ __forceinline__ unsigned ld_rlx(const unsigned* p) {
    return __hip_atomic_load(p, __ATOMIC_RELAXED, __HIP_MEMORY_SCOPE_AGENT);
}
__device__ __forceinline__ void st_rlx(unsigned* p, unsigned v) {
    __hip_atomic_store(p, v, __ATOMIC_RELAXED, __HIP_MEMORY_SCOPE_AGENT);
}

// Exact fp32, reference op order, no FMA contraction:
__device__ __forceinline__ float sqdist3(float x, float y, float z,
                                         float cx, float cy, float cz) {
    float dx = __fsub_rn(x, cx);
    float dy = __fsub_rn(y, cy);
    float dz = __fsub_rn(z, cz);
    return __fadd_rn(__fadd_rn(__fmul_rn(dx, dx), __fmul_rn(dy, dy)),
                     __fmul_rn(dz, dz));
}

__global__ void __launch_bounds__(NTHR, 1)
fps_kernel(const float* __restrict__ xyz, const float* __restrict__ feat,
           float* __restrict__ out, unsigned* __restrict__ ws) {
    // XCD-affine decode: all 16 WGs of a batch share blockIdx (mod 8), i.e.
    // one XCD under round-robin dispatch. Pure perf assumption (G16-safe:
    // wrong mapping only triggers the sticky agent fallback).
    const unsigned B = blockIdx.x;
    const int b  = (int)(B & 15u);
    const int wg = (int)(B >> 4);
    const int tid  = threadIdx.x;
    const int lane = tid & 63;
    const int wave = tid >> 6;

    unsigned* wA  = ws;             // ARRD dwords
    unsigned* wBh = ws + ARRD;      // ARRD dwords
    unsigned* wBl = ws + 2 * ARRD;  // ARRD dwords

    __shared__ int   sel[NS];      // selected indices (for the final gather)
    __shared__ float cent[3];      // current centroid (for waves 1..3)

    const float* bx  = xyz + (size_t)b * NPTS * 3;
    const int   base = wg * CHUNK;

    // One-time chunk load global -> registers (SoA in regs).
    float rx[PPT], ry[PPT], rz[PPT], dmin[PPT];
#pragma unroll
    for (int k = 0; k < PPT; ++k) {
        int g = base + tid + k * NTHR;
        rx[k] = bx[3 * g + 0];
        ry[k] = bx[3 * g + 1];
        rz[k] = bx[3 * g + 2];
        dmin[k] = 1e10f;                              // reference BIG
    }

    // Seed point 0. Wave 0 keeps the centroid in registers.
    float ncx = bx[0], ncy = bx[1], ncz = bx[2];
    if (tid == 0) {
        sel[0] = 0;
        cent[0] = ncx; cent[1] = ncy; cent[2] = ncz;
    }
    __syncthreads();

    bool pfast = true;   // sticky per-lane fast-poll flag (wave 0 only)

    for (int it = 1; it < NS; ++it) {
        float cx, cy, cz;
        if (wave == 0) { cx = ncx;     cy = ncy;     cz = ncz;     }
        else           { cx = cent[0]; cy = cent[1]; cz = cent[2]; }

        float bd = -1.0f; int bi = 0;
#pragma unroll
        for (int k = 0; k < PPT; ++k) {
            float d  = sqdist3(rx[k], ry[k], rz[k], cx, cy, cz);
            float dm = fminf(dmin[k], d);
            dmin[k] = dm;
            if (dm > bd) { bd = dm; bi = base + tid + k * NTHR; } // strict > keeps min idx
        }
        // wave reduction: max dist, tie -> min global index
        for (int off = 32; off >= 1; off >>= 1) {
            float od = __shfl_down(bd, off, 64);
            int   oi = __shfl_down(bi, off, 64);
            if (od > bd || (od == bd && oi < bi)) { bd = od; bi = oi; }
        }

        const unsigned wt = (unsigned)it;
        const size_t sb = ((size_t)(it & 1) * NB + b) * NSLOT;

        // each wave's lane 0 publishes its wave-local argmax directly
        if (lane == 0) {
            const unsigned db = __float_as_uint(bd);
            const unsigned va = (wt << 16) | (unsigned)bi;
            const unsigned vh = (wt << 16) | (db >> 16);
            const unsigned vl = (wt << 16) | (db & 0xFFFFu);
            const size_t s = sb + (size_t)(wg * NWAVE + wave);
            unsigned* qa = wA  + s;
            unsigned* qh = wBh + s;
            unsigned* ql = wBl + s;
            // 1) plain stores: write-through L1 -> own-XCD shared L2
            //    (fast visibility for same-XCD sc0 pollers)
            asm volatile(
                "global_store_dword %0, %3, off\n\t"
                "global_store_dword %1, %4, off\n\t"
                "global_store_dword %2, %5, off"
                :: "v"(qa), "v"(qh), "v"(ql), "v"(va), "v"(vh), "v"(vl)
                : "memory");
            // 2) agent stores, same addr/value (LLC path for degraded or
            //    cross-XCD pollers). Plain-before-agent: per-location
            //    same-thread ordering removes any stale-dirty-writeback
            //    hazard at the LLC.
            st_rlx(qa, va);
            st_rlx(qh, vh);
            st_rlx(ql, vl);
        }

        if (wave == 0) {
            // 64 lanes poll one sub-slot each; 3 tagged words in flight
            // together -> single round-trip detect.
            const unsigned* pa = wA  + sb + lane;
            const unsigned* ph = wBh + sb + lane;
            const unsigned* pl = wBl + sb + lane;
            unsigned a, h, l;
            int spins = 0;
            for (;;) {
                if (pfast) {
                    asm volatile(
                        "global_load_dword %0, %3, off sc0\n\t"
                        "global_load_dword %1, %4, off sc0\n\t"
                        "global_load_dword %2, %5, off sc0\n\t"
                        "s_waitcnt vmcnt(0)"
                        : "=&v"(a), "=&v"(h), "=&v"(l)
                        : "v"(pa), "v"(ph), "v"(pl)
                        : "memory");
                    if ((a >> 16) == wt && (h >> 16) == wt && (l >> 16) == wt)
                        break;
                    if (++spins > 4096) pfast = false;  // sticky degrade
                } else {
                    a = ld_rlx(pa); h = ld_rlx(ph); l = ld_rlx(pl);
                    if ((a >> 16) == wt && (h >> 16) == wt && (l >> 16) == wt)
                        break;
                    __builtin_amdgcn_s_sleep(1);
                }
            }
            float d2 = __uint_as_float((h << 16) | (l & 0xFFFFu));
            int   i2 = (int)(a & 0xFFFFu);
            // prefetch THIS candidate's coords (overlaps with the reduce)
            float px = bx[3 * i2 + 0];
            float py = bx[3 * i2 + 1];
            float pz = bx[3 * i2 + 2];
            int   wl = lane;                          // winning lane tracker
            for (int off = 32; off >= 1; off >>= 1) {
                float od = __shfl_down(d2, off, 64);
                int   oi = __shfl_down(i2, off, 64);
                int   ol = __shfl_down(wl, off, 64);
                if (lane + off < 64) {
                    if (od > d2 || (od == d2 && oi < i2)) {
                        d2 = od; i2 = oi; wl = ol;
                    }
                }
            }
            int w = __shfl(wl, 0, 64);                // winner lane, broadcast
            ncx = __shfl(px, w, 64);
            ncy = __shfl(py, w, 64);
            ncz = __shfl(pz, w, 64);
            if (lane == 0) {
                sel[it] = i2;                         // lane 0 holds winner
                cent[0] = ncx; cent[1] = ncy; cent[2] = ncz;
            }
        }
        __syncthreads();   // release new centroid to waves 1..3
    }

    // Gather: this WG writes samples [wg*32, wg*32+32).
    const float* bf   = feat + (size_t)b * NPTS * 64;
    float*       oxyz = out + (size_t)b * NS * 3;
    float*       of   = out + (size_t)NB * NS * 3 + (size_t)b * NS * 64;
    const int c  = tid & 63;
    const int sr = tid >> 6;                          // 0..3
    for (int k = 0; k < SPW / NWAVE; ++k) {
        int s = wg * SPW + k * NWAVE + sr;
        int p = sel[s];
        of[(size_t)s * 64 + c] = bf[(size_t)p * 64 + c];
    }
    if (tid < SPW * 3) {
        int s    = wg * SPW + tid / 3;
        int comp = tid % 3;
        oxyz[s * 3 + comp] = bx[sel[s] * 3 + comp];
    }
}

extern "C" void kernel_launch(void* const* d_in, const int* in_sizes, int n_in,
                              void* d_out, int out_size, void* d_ws, size_t ws_size,
                              hipStream_t stream) {
    const float* xyz = (const float*)d_in[0];
    const float* f   = (const float*)d_in[1];
    float* out = (float*)d_out;
    unsigned* ws = (unsigned*)d_ws;
    // Zero all three slot arrays (tag 0 blocks it>=1 for both parities).
    hipMemsetAsync(ws, 0, (size_t)3 * ARRD * sizeof(unsigned), stream);
    fps_kernel<<<dim3(NB * WPB), dim3(NTHR), 0, stream>>>(xyz, f, out, ws);
}